// Round 1
// baseline (1219.607 us; speedup 1.0000x reference)
//
#include <hip/hip_runtime.h>
#include <hip/hip_bf16.h>
#include <stdint.h>

typedef __bf16 bf16;
typedef bf16 bf16x8 __attribute__((ext_vector_type(8)));
typedef bf16 bf16x4 __attribute__((ext_vector_type(4)));
typedef bf16 bf16x2 __attribute__((ext_vector_type(2)));
typedef float f32x4 __attribute__((ext_vector_type(4)));

#define MFMA16(a, b, c) __builtin_amdgcn_mfma_f32_16x16x32_bf16((a), (b), (c), 0, 0, 0)

// ---- convert+transpose weights to bf16: wqkvT[co][c], wprojT[co][c] ----
__global__ void wconv_kernel(const float* __restrict__ w_qkv,
                             const float* __restrict__ w_proj,
                             bf16* __restrict__ wqkvT,
                             bf16* __restrict__ wprojT)
{
    int id = blockIdx.x * 256 + threadIdx.x;
    if (id < 49152) {                       // 384*128
        int co = id >> 7, c = id & 127;
        wqkvT[id] = (bf16)w_qkv[c * 384 + co];
    } else {
        int id2 = id - 49152;               // 128*128
        int co = id2 >> 7, c = id2 & 127;
        wprojT[id2] = (bf16)w_proj[c * 128 + co];
    }
}

// ---- fused window/grid relative attention, one 8x8 window per block ----
// STAGE 0: pixel = (wr*8+i, wc*8+j)   (window partition)
// STAGE 1: pixel = (i*32+wr, j*32+wc) (grid partition)
template<int STAGE>
__global__ __launch_bounds__(256, 2)
void attn_kernel(const float* xsrc, float* dst,
                 const bf16* __restrict__ wqkvT, const bf16* __restrict__ wprojT,
                 const float* __restrict__ b_qkv, const float* __restrict__ b_proj,
                 const float* __restrict__ rpb)
{
    __shared__ bf16 s_xw[64 * 128];      // input window (bf16); later attn output [n][c]
    __shared__ bf16 s_qk[4 * 2 * 64 * 32]; // per-head q,k; per-head P aliases q|k (4096 elems)
    __shared__ bf16 s_vT[4 * 32 * 64];   // per-head V^T [d][m]
    __shared__ float s_rpb[225 * 4];

    const int tid = threadIdx.x;
    const int lane = tid & 63;
    const int wv = tid >> 6;     // wave = head = GEMM column chunk
    const int lr = lane & 15;
    const int lg = lane >> 4;

    const int blk = blockIdx.x;
    const int b  = blk >> 10;
    const int wr = (blk >> 5) & 31;
    const int wc = blk & 31;

    // ---- stage input window into LDS (bf16, XOR-swizzled rows) ----
    {
        int n = tid & 63;
        int ii = n >> 3, jj = n & 7;
        int ph = (STAGE == 0) ? (wr * 8 + ii) : (ii * 32 + wr);
        int pw = (STAGE == 0) ? (wc * 8 + jj) : (jj * 32 + wc);
        const float* px = xsrc + (size_t)b * 128 * 65536 + ph * 256 + pw;
        int cp0 = tid >> 6;
#pragma unroll
        for (int t = 0; t < 16; ++t) {
            int c = (cp0 + t * 4) * 2;
            float f0 = px[(size_t)c * 65536];
            float f1 = px[(size_t)(c + 1) * 65536];
            bf16x2 pr; pr[0] = (bf16)f0; pr[1] = (bf16)f1;
            int idx = (n * 128 + c) ^ ((n & 15) << 3);
            *(bf16x2*)&s_xw[idx] = pr;
        }
    }
    for (int i = tid; i < 900; i += 256) s_rpb[i] = rpb[i];

    // preload qkv weight B-fragments (this wave's 96 output cols), overlaps staging
    bf16x8 wB[6][4];
#pragma unroll
    for (int nt = 0; nt < 6; ++nt) {
        int co = wv * 96 + nt * 16 + lr;
        const bf16* rp = wqkvT + co * 128 + lg * 8;
#pragma unroll
        for (int ks = 0; ks < 4; ++ks)
            wB[nt][ks] = *(const bf16x8*)(rp + ks * 32);
    }

    __syncthreads();

    // ---- QKV GEMM: qkv[n][co] = sum_c xw[n][c] * wqkv[c][co] ----
    f32x4 qacc[4][6];
#pragma unroll
    for (int mt = 0; mt < 4; ++mt)
#pragma unroll
        for (int nt = 0; nt < 6; ++nt)
            qacc[mt][nt] = (f32x4){0.f, 0.f, 0.f, 0.f};

#pragma unroll
    for (int ks = 0; ks < 4; ++ks) {
        bf16x8 a[4];
#pragma unroll
        for (int mt = 0; mt < 4; ++mt) {
            int n = mt * 16 + lr;
            a[mt] = *(const bf16x8*)&s_xw[(n * 128 + ks * 32 + lg * 8) ^ ((n & 15) << 3)];
        }
#pragma unroll
        for (int mt = 0; mt < 4; ++mt)
#pragma unroll
            for (int nt = 0; nt < 6; ++nt)
                qacc[mt][nt] = MFMA16(a[mt], wB[nt][ks], qacc[mt][nt]);
    }

    // scatter q,k (rows n, cols d) and v^T (rows d, cols m) into per-head LDS, + bias
#pragma unroll
    for (int nt = 0; nt < 6; ++nt) {
        int co = wv * 96 + nt * 16 + lr;
        float bias = b_qkv[co];
        int qsel = co >> 7;          // 0=q 1=k 2=v (uniform per nt)
        int hh = (co >> 5) & 3;
        int d = co & 31;
#pragma unroll
        for (int mt = 0; mt < 4; ++mt) {
            int n0 = mt * 16 + lg * 4;
            if (qsel < 2) {
#pragma unroll
                for (int r = 0; r < 4; ++r) {
                    int n = n0 + r;
                    int idx = (((hh * 2 + qsel) * 64 + n) * 32 + d) ^ ((n & 3) << 3);
                    s_qk[idx] = (bf16)(qacc[mt][nt][r] + bias);
                }
            } else {
                bf16x4 v4;
#pragma unroll
                for (int r = 0; r < 4; ++r) v4[r] = (bf16)(qacc[mt][nt][r] + bias);
                int idx = ((hh * 32 + d) * 64 + n0) ^ ((d & 7) << 3);
                *(bf16x4*)&s_vT[idx] = v4;
            }
        }
    }

    __syncthreads();

    // ---- attention, head h = wv.  S^T = K*Q^T so softmax rows are mostly lane-local
    const int h = wv;
    f32x4 sacc[4][4];   // [mt][nt]: S^T[m][n], m=mt*16+lg*4+r, n=nt*16+lr
#pragma unroll
    for (int mt = 0; mt < 4; ++mt)
#pragma unroll
        for (int nt = 0; nt < 4; ++nt)
            sacc[mt][nt] = (f32x4){0.f, 0.f, 0.f, 0.f};
    {
        bf16x8 ka[4], qb[4];
#pragma unroll
        for (int t = 0; t < 4; ++t) {
            int m = t * 16 + lr;
            ka[t] = *(const bf16x8*)&s_qk[(((h * 2 + 1) * 64 + m) * 32 + lg * 8) ^ ((m & 3) << 3)];
            qb[t] = *(const bf16x8*)&s_qk[(((h * 2 + 0) * 64 + m) * 32 + lg * 8) ^ ((m & 3) << 3)];
        }
#pragma unroll
        for (int mt = 0; mt < 4; ++mt)
#pragma unroll
            for (int nt = 0; nt < 4; ++nt)
                sacc[mt][nt] = MFMA16(ka[mt], qb[nt], sacc[mt][nt]);
    }

    // scale 0.5 (= HEADS^-0.5), + Swin relative bias, softmax over m
    float inv[4];
#pragma unroll
    for (int nt = 0; nt < 4; ++nt) {
        int n = nt * 16 + lr;
        float mx = -1e30f;
#pragma unroll
        for (int mt = 0; mt < 4; ++mt)
#pragma unroll
            for (int r = 0; r < 4; ++r) {
                int m = mt * 16 + lg * 4 + r;
                int rel = ((n >> 3) - (m >> 3) + 7) * 15 + ((n & 7) - (m & 7) + 7);
                float lgt = sacc[mt][nt][r] * 0.5f + s_rpb[rel * 4 + h];
                sacc[mt][nt][r] = lgt;
                mx = fmaxf(mx, lgt);
            }
        mx = fmaxf(mx, __shfl_xor(mx, 16));
        mx = fmaxf(mx, __shfl_xor(mx, 32));
        float sum = 0.f;
#pragma unroll
        for (int mt = 0; mt < 4; ++mt)
#pragma unroll
            for (int r = 0; r < 4; ++r) {
                float p = __expf(sacc[mt][nt][r] - mx);
                sacc[mt][nt][r] = p;
                sum += p;
            }
        sum += __shfl_xor(sum, 16);
        sum += __shfl_xor(sum, 32);
        inv[nt] = 1.f / sum;
    }

    // write P as [n][m] bf16 into this head's (dead) q/k region
    bf16* s_p = s_qk + h * 4096;
#pragma unroll
    for (int nt = 0; nt < 4; ++nt) {
        int n = nt * 16 + lr;
#pragma unroll
        for (int mt = 0; mt < 4; ++mt) {
            bf16x4 v4;
#pragma unroll
            for (int r = 0; r < 4; ++r) v4[r] = (bf16)(sacc[mt][nt][r] * inv[nt]);
            int idx = (n * 64 + mt * 16 + lg * 4) ^ ((n & 7) << 3);
            *(bf16x4*)&s_p[idx] = v4;
        }
    }
    asm volatile("s_waitcnt lgkmcnt(0)" ::: "memory"); // wave-local P visible to all lanes

    // PV: out^T[d][n] = sum_m V^T[d][m] * P^T[m][n]
    f32x4 oacc[2][4];
#pragma unroll
    for (int dt = 0; dt < 2; ++dt)
#pragma unroll
        for (int nt = 0; nt < 4; ++nt)
            oacc[dt][nt] = (f32x4){0.f, 0.f, 0.f, 0.f};
#pragma unroll
    for (int ks = 0; ks < 2; ++ks) {
        bf16x8 va[2], pb[4];
#pragma unroll
        for (int dt = 0; dt < 2; ++dt) {
            int d = dt * 16 + lr;
            va[dt] = *(const bf16x8*)&s_vT[((h * 32 + d) * 64 + ks * 32 + lg * 8) ^ ((d & 7) << 3)];
        }
#pragma unroll
        for (int nt = 0; nt < 4; ++nt) {
            int n = nt * 16 + lr;
            pb[nt] = *(const bf16x8*)&s_p[(n * 64 + ks * 32 + lg * 8) ^ ((n & 7) << 3)];
        }
#pragma unroll
        for (int dt = 0; dt < 2; ++dt)
#pragma unroll
            for (int nt = 0; nt < 4; ++nt)
                oacc[dt][nt] = MFMA16(va[dt], pb[nt], oacc[dt][nt]);
    }

    // attn output -> s_xw as [n][c], c = h*32 + d
#pragma unroll
    for (int dt = 0; dt < 2; ++dt)
#pragma unroll
        for (int nt = 0; nt < 4; ++nt) {
            int n = nt * 16 + lr;
            int c0 = h * 32 + dt * 16 + lg * 4;
            bf16x4 v4;
#pragma unroll
            for (int r = 0; r < 4; ++r) v4[r] = (bf16)oacc[dt][nt][r];
            int idx = (n * 128 + c0) ^ ((n & 15) << 3);
            *(bf16x4*)&s_xw[idx] = v4;
        }

    __syncthreads();

    // ---- proj + residual:  x1^T[co][n] = sum_c wproj[c][co] * attn[n][c] ----
    f32x4 pacc[2][4];
#pragma unroll
    for (int ct = 0; ct < 2; ++ct)
#pragma unroll
        for (int nt = 0; nt < 4; ++nt)
            pacc[ct][nt] = (f32x4){0.f, 0.f, 0.f, 0.f};
#pragma unroll
    for (int ks = 0; ks < 4; ++ks) {
        bf16x8 wa[2], ab[4];
#pragma unroll
        for (int ct = 0; ct < 2; ++ct) {
            int co = wv * 32 + ct * 16 + lr;
            wa[ct] = *(const bf16x8*)(wprojT + co * 128 + ks * 32 + lg * 8);
        }
#pragma unroll
        for (int nt = 0; nt < 4; ++nt) {
            int n = nt * 16 + lr;
            ab[nt] = *(const bf16x8*)&s_xw[(n * 128 + ks * 32 + lg * 8) ^ ((n & 15) << 3)];
        }
#pragma unroll
        for (int ct = 0; ct < 2; ++ct)
#pragma unroll
            for (int nt = 0; nt < 4; ++nt)
                pacc[ct][nt] = MFMA16(wa[ct], ab[nt], pacc[ct][nt]);
    }

#pragma unroll
    for (int ct = 0; ct < 2; ++ct)
#pragma unroll
        for (int nt = 0; nt < 4; ++nt) {
            int n = nt * 16 + lr;
            int ii = n >> 3, jj = n & 7;
            int ph = (STAGE == 0) ? (wr * 8 + ii) : (ii * 32 + wr);
            int pw = (STAGE == 0) ? (wc * 8 + jj) : (jj * 32 + wc);
#pragma unroll
            for (int r = 0; r < 4; ++r) {
                int cout = wv * 32 + ct * 16 + lg * 4 + r;
                size_t addr = ((size_t)(b * 128 + cout)) * 65536 + (size_t)ph * 256 + pw;
                dst[addr] = xsrc[addr] + b_proj[cout] + pacc[ct][nt][r];
            }
        }
}

// ---- channel pooling: avg & max over H*W per (b,c) ----
__global__ void pool_kernel(const float* __restrict__ x, float* __restrict__ avg,
                            float* __restrict__ mx)
{
    int bc = blockIdx.x;
    const float4* p = (const float4*)(x + (size_t)bc * 65536);
    int tid = threadIdx.x;
    float s = 0.f, m = -1e30f;
    for (int i = 0; i < 64; ++i) {
        float4 v = p[tid + i * 256];
        s += v.x + v.y + v.z + v.w;
        m = fmaxf(m, fmaxf(fmaxf(v.x, v.y), fmaxf(v.z, v.w)));
    }
    for (int o = 32; o; o >>= 1) { s += __shfl_xor(s, o); m = fmaxf(m, __shfl_xor(m, o)); }
    __shared__ float ls[4], lm[4];
    int wv = tid >> 6;
    if ((tid & 63) == 0) { ls[wv] = s; lm[wv] = m; }
    __syncthreads();
    if (tid == 0) {
        avg[bc] = (ls[0] + ls[1] + ls[2] + ls[3]) * (1.f / 65536.f);
        mx[bc]  = fmaxf(fmaxf(lm[0], lm[1]), fmaxf(lm[2], lm[3]));
    }
}

// ---- gate = sigmoid( (relu(avg@W1)+relu(mx@W1)) @ W2 ) ----
__global__ void gate_kernel(const float* __restrict__ avg, const float* __restrict__ mx,
                            const float* __restrict__ w1, const float* __restrict__ w2,
                            float* __restrict__ gate)
{
    __shared__ float la[512], lm[512], s1[512];
    int t = threadIdx.x;
    la[t] = avg[t]; lm[t] = mx[t];
    __syncthreads();
    int b = t >> 7, co = t & 127;
    float a1 = 0.f, m1 = 0.f;
    for (int c = 0; c < 128; ++c) {
        float w = w1[c * 128 + co];
        a1 += la[b * 128 + c] * w;
        m1 += lm[b * 128 + c] * w;
    }
    s1[t] = fmaxf(a1, 0.f) + fmaxf(m1, 0.f);
    __syncthreads();
    float g = 0.f;
    for (int c = 0; c < 128; ++c) g += s1[b * 128 + c] * w2[c * 128 + co];
    gate[t] = 1.f / (1.f + __expf(-g));
}

// ---- x2 * gate, in place ----
__global__ void mul_kernel(float* __restrict__ out, const float* __restrict__ gate)
{
    int stride = gridDim.x * blockDim.x;
    float4* o = (float4*)out;
    for (int i = blockIdx.x * blockDim.x + threadIdx.x; i < 8388608; i += stride) {
        float g = gate[i >> 14];
        float4 v = o[i];
        v.x *= g; v.y *= g; v.z *= g; v.w *= g;
        o[i] = v;
    }
}

extern "C" void kernel_launch(void* const* d_in, const int* in_sizes, int n_in,
                              void* d_out, int out_size, void* d_ws, size_t ws_size,
                              hipStream_t stream)
{
    const float* x      = (const float*)d_in[0];
    const float* w_qkv  = (const float*)d_in[1];
    const float* b_qkv  = (const float*)d_in[2];
    const float* w_proj = (const float*)d_in[3];
    const float* b_proj = (const float*)d_in[4];
    const float* rpb    = (const float*)d_in[5];
    const float* cf_w1  = (const float*)d_in[6];
    const float* cf_w2  = (const float*)d_in[7];
    float* out = (float*)d_out;

    char* ws = (char*)d_ws;
    bf16*  wqkvT  = (bf16*)ws;                 // 98304 B
    bf16*  wprojT = (bf16*)(ws + 98304);       // 32768 B
    float* avg    = (float*)(ws + 131072);     // 2048 B
    float* mxp    = (float*)(ws + 133120);     // 2048 B
    float* gate   = (float*)(ws + 135168);     // 2048 B

    wconv_kernel<<<256, 256, 0, stream>>>(w_qkv, w_proj, wqkvT, wprojT);
    attn_kernel<0><<<4096, 256, 0, stream>>>(x,   out, wqkvT, wprojT, b_qkv, b_proj, rpb);
    attn_kernel<1><<<4096, 256, 0, stream>>>(out, out, wqkvT, wprojT, b_qkv, b_proj, rpb);
    pool_kernel<<<512, 256, 0, stream>>>(out, avg, mxp);
    gate_kernel<<<1, 512, 0, stream>>>(avg, mxp, cf_w1, cf_w2, gate);
    mul_kernel<<<2048, 256, 0, stream>>>(out, gate);
}

// Round 2
// 737.996 us; speedup vs baseline: 1.6526x; 1.6526x over previous
//
#include <hip/hip_runtime.h>
#include <hip/hip_bf16.h>
#include <stdint.h>

typedef __bf16 bf16;
typedef bf16 bf16x8 __attribute__((ext_vector_type(8)));
typedef bf16 bf16x4 __attribute__((ext_vector_type(4)));
typedef bf16 bf16x2 __attribute__((ext_vector_type(2)));
typedef float f32x4 __attribute__((ext_vector_type(4)));

#define MFMA16(a, b, c) __builtin_amdgcn_mfma_f32_16x16x32_bf16((a), (b), (c), 0, 0, 0)

// ---- convert+transpose weights to bf16 + init pool atomics ----
__global__ void wconv_kernel(const float* __restrict__ w_qkv,
                             const float* __restrict__ w_proj,
                             bf16* __restrict__ wqkvT,
                             bf16* __restrict__ wprojT,
                             float* __restrict__ pool_sum,
                             unsigned* __restrict__ pool_maxkey)
{
    int id = blockIdx.x * 256 + threadIdx.x;
    if (blockIdx.x == 0 && threadIdx.x < 256) {
        pool_sum[threadIdx.x] = 0.f;        pool_maxkey[threadIdx.x] = 0u;
        pool_sum[256 + threadIdx.x] = 0.f;  pool_maxkey[256 + threadIdx.x] = 0u;
    }
    if (id < 49152) {                       // 384*128
        int co = id >> 7, c = id & 127;
        wqkvT[id] = (bf16)w_qkv[c * 384 + co];
    } else {
        int id2 = id - 49152;               // 128*128
        int co = id2 >> 7, c = id2 & 127;
        wprojT[id2] = (bf16)w_proj[c * 128 + co];
    }
}

// ---- fused window/grid relative attention, one 8x8 window per block ----
// STAGE 0: pixel = (wr*8+i, wc*8+j)   (window partition)
// STAGE 1: pixel = (i*32+wr, j*32+wc) (grid partition)  + fused pooling
template<int STAGE>
__global__ __launch_bounds__(256, 3)
void attn_kernel(const float* xsrc, float* dst,
                 const bf16* __restrict__ wqkvT, const bf16* __restrict__ wprojT,
                 const float* __restrict__ b_qkv, const float* __restrict__ b_proj,
                 const float* __restrict__ rpb,
                 float* __restrict__ pool_sum, unsigned* __restrict__ pool_maxkey)
{
    // s_a: input window [n][c] (swz)  -> later per-head V^T [4][32][64] (swz)
    // s_b: per-head q,k [4][2][64][32] -> per-head P [64][64] -> attnout [n][c] (first 16KB)
    __shared__ bf16 s_a[64 * 128];
    __shared__ bf16 s_b[4 * 2 * 64 * 32];
    __shared__ float s_rpb[225 * 4];

    const int tid = threadIdx.x;
    const int lane = tid & 63;
    const int wv = tid >> 6;     // wave = head = GEMM column chunk
    const int lr = lane & 15;
    const int lg = lane >> 4;

    // XCD-bijective swizzle: consecutive logical blocks (which share cache
    // lines) land on the same XCD and are temporally adjacent.
    const int blk = (blockIdx.x & 7) * 512 + (blockIdx.x >> 3);
    const int b  = blk >> 10;
    const int wr = (blk >> 5) & 31;
    const int wc = blk & 31;

    // ---- stage input window into LDS (bf16, XOR-swizzled rows) ----
    {
        int n = tid & 63;
        int ii = n >> 3, jj = n & 7;
        int ph = (STAGE == 0) ? (wr * 8 + ii) : (ii * 32 + wr);
        int pw = (STAGE == 0) ? (wc * 8 + jj) : (jj * 32 + wc);
        const float* px = xsrc + (size_t)b * 128 * 65536 + ph * 256 + pw;
        int cp0 = tid >> 6;
#pragma unroll
        for (int t = 0; t < 16; ++t) {
            int c = (cp0 + t * 4) * 2;
            float f0 = px[(size_t)c * 65536];
            float f1 = px[(size_t)(c + 1) * 65536];
            bf16x2 pr; pr[0] = (bf16)f0; pr[1] = (bf16)f1;
            int idx = (n * 128 + c) ^ ((n & 15) << 3);
            *(bf16x2*)&s_a[idx] = pr;
        }
    }
    for (int i = tid; i < 900; i += 256) s_rpb[i] = rpb[i];

    // preload qkv weight B-fragments (this wave's 96 output cols), overlaps staging
    bf16x8 wB[6][4];
#pragma unroll
    for (int nt = 0; nt < 6; ++nt) {
        int co = wv * 96 + nt * 16 + lr;
        const bf16* rp = wqkvT + co * 128 + lg * 8;
#pragma unroll
        for (int ks = 0; ks < 4; ++ks)
            wB[nt][ks] = *(const bf16x8*)(rp + ks * 32);
    }

    __syncthreads();

    // ---- QKV GEMM: qkv[n][co] = sum_c xw[n][c] * wqkv[c][co] ----
    f32x4 qacc[4][6];
#pragma unroll
    for (int mt = 0; mt < 4; ++mt)
#pragma unroll
        for (int nt = 0; nt < 6; ++nt)
            qacc[mt][nt] = (f32x4){0.f, 0.f, 0.f, 0.f};

#pragma unroll
    for (int ks = 0; ks < 4; ++ks) {
        bf16x8 a[4];
#pragma unroll
        for (int mt = 0; mt < 4; ++mt) {
            int n = mt * 16 + lr;
            a[mt] = *(const bf16x8*)&s_a[(n * 128 + ks * 32 + lg * 8) ^ ((n & 15) << 3)];
        }
#pragma unroll
        for (int mt = 0; mt < 4; ++mt)
#pragma unroll
            for (int nt = 0; nt < 6; ++nt)
                qacc[mt][nt] = MFMA16(a[mt], wB[nt][ks], qacc[mt][nt]);
    }

    __syncthreads();   // all waves done reading s_a before V^T overwrites it

    // scatter q,k (rows n, cols d) into s_b and v^T (rows d, cols m) into s_a, + bias
#pragma unroll
    for (int nt = 0; nt < 6; ++nt) {
        int co = wv * 96 + nt * 16 + lr;
        float bias = b_qkv[co];
        int qsel = co >> 7;          // 0=q 1=k 2=v (uniform per nt)
        int hh = (co >> 5) & 3;
        int d = co & 31;
#pragma unroll
        for (int mt = 0; mt < 4; ++mt) {
            int n0 = mt * 16 + lg * 4;
            if (qsel < 2) {
#pragma unroll
                for (int r = 0; r < 4; ++r) {
                    int n = n0 + r;
                    int idx = (((hh * 2 + qsel) * 64 + n) * 32 + d) ^ ((n & 3) << 3);
                    s_b[idx] = (bf16)(qacc[mt][nt][r] + bias);
                }
            } else {
                bf16x4 v4;
#pragma unroll
                for (int r = 0; r < 4; ++r) v4[r] = (bf16)(qacc[mt][nt][r] + bias);
                int idx = ((hh * 32 + d) * 64 + n0) ^ ((d & 7) << 3);
                *(bf16x4*)&s_a[idx] = v4;
            }
        }
    }

    __syncthreads();

    // ---- attention, head h = wv.  S^T = K*Q^T so softmax rows are mostly lane-local
    const int h = wv;
    f32x4 sacc[4][4];   // [mt][nt]: S^T[m][n], m=mt*16+lg*4+r, n=nt*16+lr
#pragma unroll
    for (int mt = 0; mt < 4; ++mt)
#pragma unroll
        for (int nt = 0; nt < 4; ++nt)
            sacc[mt][nt] = (f32x4){0.f, 0.f, 0.f, 0.f};
    {
        bf16x8 ka[4], qb[4];
#pragma unroll
        for (int t = 0; t < 4; ++t) {
            int m = t * 16 + lr;
            ka[t] = *(const bf16x8*)&s_b[(((h * 2 + 1) * 64 + m) * 32 + lg * 8) ^ ((m & 3) << 3)];
            qb[t] = *(const bf16x8*)&s_b[(((h * 2 + 0) * 64 + m) * 32 + lg * 8) ^ ((m & 3) << 3)];
        }
#pragma unroll
        for (int mt = 0; mt < 4; ++mt)
#pragma unroll
            for (int nt = 0; nt < 4; ++nt)
                sacc[mt][nt] = MFMA16(ka[mt], qb[nt], sacc[mt][nt]);
    }

    // scale 0.5 (= HEADS^-0.5), + Swin relative bias, softmax over m
    float inv[4];
#pragma unroll
    for (int nt = 0; nt < 4; ++nt) {
        int n = nt * 16 + lr;
        float mx = -1e30f;
#pragma unroll
        for (int mt = 0; mt < 4; ++mt)
#pragma unroll
            for (int r = 0; r < 4; ++r) {
                int m = mt * 16 + lg * 4 + r;
                int rel = ((n >> 3) - (m >> 3) + 7) * 15 + ((n & 7) - (m & 7) + 7);
                float lgt = sacc[mt][nt][r] * 0.5f + s_rpb[rel * 4 + h];
                sacc[mt][nt][r] = lgt;
                mx = fmaxf(mx, lgt);
            }
        mx = fmaxf(mx, __shfl_xor(mx, 16));
        mx = fmaxf(mx, __shfl_xor(mx, 32));
        float sum = 0.f;
#pragma unroll
        for (int mt = 0; mt < 4; ++mt)
#pragma unroll
            for (int r = 0; r < 4; ++r) {
                float p = __expf(sacc[mt][nt][r] - mx);
                sacc[mt][nt][r] = p;
                sum += p;
            }
        sum += __shfl_xor(sum, 16);
        sum += __shfl_xor(sum, 32);
        inv[nt] = 1.f / sum;
    }

    // write P as [n][m] bf16 into this head's (dead) q/k region
    bf16* s_p = s_b + h * 4096;
#pragma unroll
    for (int nt = 0; nt < 4; ++nt) {
        int n = nt * 16 + lr;
#pragma unroll
        for (int mt = 0; mt < 4; ++mt) {
            bf16x4 v4;
#pragma unroll
            for (int r = 0; r < 4; ++r) v4[r] = (bf16)(sacc[mt][nt][r] * inv[nt]);
            int idx = (n * 64 + mt * 16 + lg * 4) ^ ((n & 7) << 3);
            *(bf16x4*)&s_p[idx] = v4;
        }
    }
    asm volatile("s_waitcnt lgkmcnt(0)" ::: "memory"); // wave-local P visible to all lanes
    __builtin_amdgcn_sched_barrier(0);

    // PV: out^T[d][n] = sum_m V^T[d][m] * P^T[m][n]
    f32x4 oacc[2][4];
#pragma unroll
    for (int dt = 0; dt < 2; ++dt)
#pragma unroll
        for (int nt = 0; nt < 4; ++nt)
            oacc[dt][nt] = (f32x4){0.f, 0.f, 0.f, 0.f};
#pragma unroll
    for (int ks = 0; ks < 2; ++ks) {
        bf16x8 va[2], pb[4];
#pragma unroll
        for (int dt = 0; dt < 2; ++dt) {
            int d = dt * 16 + lr;
            va[dt] = *(const bf16x8*)&s_a[((h * 32 + d) * 64 + ks * 32 + lg * 8) ^ ((d & 7) << 3)];
        }
#pragma unroll
        for (int nt = 0; nt < 4; ++nt) {
            int n = nt * 16 + lr;
            pb[nt] = *(const bf16x8*)&s_p[(n * 64 + ks * 32 + lg * 8) ^ ((n & 7) << 3)];
        }
#pragma unroll
        for (int dt = 0; dt < 2; ++dt)
#pragma unroll
            for (int nt = 0; nt < 4; ++nt)
                oacc[dt][nt] = MFMA16(va[dt], pb[nt], oacc[dt][nt]);
    }

    __syncthreads();   // all PV reads of s_b done before attnout overwrites it

    // attn output -> s_b (first 16KB) as [n][c], c = h*32 + d
#pragma unroll
    for (int dt = 0; dt < 2; ++dt)
#pragma unroll
        for (int nt = 0; nt < 4; ++nt) {
            int n = nt * 16 + lr;
            int c0 = h * 32 + dt * 16 + lg * 4;
            bf16x4 v4;
#pragma unroll
            for (int r = 0; r < 4; ++r) v4[r] = (bf16)oacc[dt][nt][r];
            int idx = (n * 128 + c0) ^ ((n & 15) << 3);
            *(bf16x4*)&s_b[idx] = v4;
        }

    __syncthreads();

    // ---- proj + residual:  x1^T[co][n] = sum_c wproj[c][co] * attn[n][c] ----
    f32x4 pacc[2][4];
#pragma unroll
    for (int ct = 0; ct < 2; ++ct)
#pragma unroll
        for (int nt = 0; nt < 4; ++nt)
            pacc[ct][nt] = (f32x4){0.f, 0.f, 0.f, 0.f};
#pragma unroll
    for (int ks = 0; ks < 4; ++ks) {
        bf16x8 wa[2], ab[4];
#pragma unroll
        for (int ct = 0; ct < 2; ++ct) {
            int co = wv * 32 + ct * 16 + lr;
            wa[ct] = *(const bf16x8*)(wprojT + co * 128 + ks * 32 + lg * 8);
        }
#pragma unroll
        for (int nt = 0; nt < 4; ++nt) {
            int n = nt * 16 + lr;
            ab[nt] = *(const bf16x8*)&s_b[(n * 128 + ks * 32 + lg * 8) ^ ((n & 15) << 3)];
        }
#pragma unroll
        for (int ct = 0; ct < 2; ++ct)
#pragma unroll
            for (int nt = 0; nt < 4; ++nt)
                pacc[ct][nt] = MFMA16(wa[ct], ab[nt], pacc[ct][nt]);
    }

    float ps[2][4], pm[2][4];
    if constexpr (STAGE == 1) {
#pragma unroll
        for (int ct = 0; ct < 2; ++ct)
#pragma unroll
            for (int r = 0; r < 4; ++r) { ps[ct][r] = 0.f; pm[ct][r] = -1e30f; }
    }

#pragma unroll
    for (int ct = 0; ct < 2; ++ct)
#pragma unroll
        for (int nt = 0; nt < 4; ++nt) {
            int n = nt * 16 + lr;
            int ii = n >> 3, jj = n & 7;
            int ph = (STAGE == 0) ? (wr * 8 + ii) : (ii * 32 + wr);
            int pw = (STAGE == 0) ? (wc * 8 + jj) : (jj * 32 + wc);
#pragma unroll
            for (int r = 0; r < 4; ++r) {
                int cout = wv * 32 + ct * 16 + lg * 4 + r;
                size_t addr = ((size_t)(b * 128 + cout)) * 65536 + (size_t)ph * 256 + pw;
                float v = xsrc[addr] + b_proj[cout] + pacc[ct][nt][r];
                dst[addr] = v;
                if constexpr (STAGE == 1) {
                    ps[ct][r] += v;
                    pm[ct][r] = fmaxf(pm[ct][r], v);
                }
            }
        }

    // ---- fused channel pooling partials (stage 1 only) ----
    if constexpr (STAGE == 1) {
#pragma unroll
        for (int ct = 0; ct < 2; ++ct)
#pragma unroll
            for (int r = 0; r < 4; ++r) {
                float s = ps[ct][r], m = pm[ct][r];
#pragma unroll
                for (int o = 1; o < 16; o <<= 1) {
                    s += __shfl_xor(s, o);
                    m = fmaxf(m, __shfl_xor(m, o));
                }
                if (lr == 0) {
                    int cout = wv * 32 + ct * 16 + lg * 4 + r;
                    atomicAdd(&pool_sum[b * 128 + cout], s);
                    unsigned u = __float_as_uint(m);
                    unsigned kk = (u & 0x80000000u) ? ~u : (u | 0x80000000u);
                    atomicMax(&pool_maxkey[b * 128 + cout], kk);
                }
            }
    }
}

// ---- gate = sigmoid( (relu(avg@W1)+relu(mx@W1)) @ W2 ) ----
__global__ void gate_kernel(const float* __restrict__ pool_sum,
                            const unsigned* __restrict__ pool_maxkey,
                            const float* __restrict__ w1, const float* __restrict__ w2,
                            float* __restrict__ gate)
{
    __shared__ float la[512], lm[512], s1[512];
    int t = threadIdx.x;
    la[t] = pool_sum[t] * (1.f / 65536.f);
    unsigned k = pool_maxkey[t];
    lm[t] = __uint_as_float((k & 0x80000000u) ? (k ^ 0x80000000u) : ~k);
    __syncthreads();
    int b = t >> 7, co = t & 127;
    float a1 = 0.f, m1 = 0.f;
    for (int c = 0; c < 128; ++c) {
        float w = w1[c * 128 + co];
        a1 += la[b * 128 + c] * w;
        m1 += lm[b * 128 + c] * w;
    }
    s1[t] = fmaxf(a1, 0.f) + fmaxf(m1, 0.f);
    __syncthreads();
    float g = 0.f;
    for (int c = 0; c < 128; ++c) g += s1[b * 128 + c] * w2[c * 128 + co];
    gate[t] = 1.f / (1.f + __expf(-g));
}

// ---- x2 * gate, in place ----
__global__ void mul_kernel(float* __restrict__ out, const float* __restrict__ gate)
{
    int stride = gridDim.x * blockDim.x;
    float4* o = (float4*)out;
    for (int i = blockIdx.x * blockDim.x + threadIdx.x; i < 8388608; i += stride) {
        float g = gate[i >> 14];
        float4 v = o[i];
        v.x *= g; v.y *= g; v.z *= g; v.w *= g;
        o[i] = v;
    }
}

extern "C" void kernel_launch(void* const* d_in, const int* in_sizes, int n_in,
                              void* d_out, int out_size, void* d_ws, size_t ws_size,
                              hipStream_t stream)
{
    const float* x      = (const float*)d_in[0];
    const float* w_qkv  = (const float*)d_in[1];
    const float* b_qkv  = (const float*)d_in[2];
    const float* w_proj = (const float*)d_in[3];
    const float* b_proj = (const float*)d_in[4];
    const float* rpb    = (const float*)d_in[5];
    const float* cf_w1  = (const float*)d_in[6];
    const float* cf_w2  = (const float*)d_in[7];
    float* out = (float*)d_out;

    char* ws = (char*)d_ws;
    bf16*     wqkvT   = (bf16*)ws;                 // 98304 B
    bf16*     wprojT  = (bf16*)(ws + 98304);       // 32768 B
    float*    poolsum = (float*)(ws + 131072);     // 2048 B
    unsigned* poolmax = (unsigned*)(ws + 133120);  // 2048 B
    float*    gate    = (float*)(ws + 135168);     // 2048 B

    wconv_kernel<<<256, 256, 0, stream>>>(w_qkv, w_proj, wqkvT, wprojT, poolsum, poolmax);
    attn_kernel<0><<<4096, 256, 0, stream>>>(x,   out, wqkvT, wprojT, b_qkv, b_proj, rpb,
                                             poolsum, poolmax);
    attn_kernel<1><<<4096, 256, 0, stream>>>(out, out, wqkvT, wprojT, b_qkv, b_proj, rpb,
                                             poolsum, poolmax);
    gate_kernel<<<1, 512, 0, stream>>>(poolsum, poolmax, cf_w1, cf_w2, gate);
    mul_kernel<<<2048, 256, 0, stream>>>(out, gate);
}

// Round 3
// 390.660 us; speedup vs baseline: 3.1219x; 1.8891x over previous
//
#include <hip/hip_runtime.h>
#include <hip/hip_bf16.h>
#include <stdint.h>

typedef __bf16 bf16;
typedef bf16 bf16x8 __attribute__((ext_vector_type(8)));
typedef bf16 bf16x4 __attribute__((ext_vector_type(4)));
typedef float f32x4 __attribute__((ext_vector_type(4)));

#define MFMA16(a, b, c) __builtin_amdgcn_mfma_f32_16x16x32_bf16((a), (b), (c), 0, 0, 0)
#define QKSWZ(n) ((((n) >> 2) & 3) << 3)
#define QKS 40        // q/k LDS row stride (elems): 80 B -> lg groups hit distinct bank sets
#define QKR 2560      // 64*QKS, one q-or-k region per head

// ---- k0: x [B,C,H,W] fp32 -> xT [B,H,W,C] bf16 (tiled LDS transpose) ----
__global__ __launch_bounds__(256) void tin_kernel(const float* __restrict__ x,
                                                  bf16* __restrict__ xT)
{
    __shared__ float s[128 * 65];
    const int blk = blockIdx.x;            // b*1024 + pxchunk
    const int b = blk >> 10;
    const int px0 = (blk & 1023) * 64;
    const int tid = threadIdx.x;
    {
        int c0 = tid >> 6, pxl = tid & 63;
        const float* src = x + (size_t)b * 8388608 + px0 + pxl;
#pragma unroll
        for (int i = 0; i < 32; ++i) {
            int c = c0 + i * 4;
            s[c * 65 + pxl] = src[(size_t)c * 65536];
        }
    }
    __syncthreads();
    int px = tid >> 2, piece = tid & 3;
    bf16* dstp = xT + ((size_t)b * 65536 + px0 + px) * 128;
#pragma unroll
    for (int k = 0; k < 4; ++k) {
        bf16x8 v8;
        int cb = (k * 4 + piece) * 8;
#pragma unroll
        for (int j = 0; j < 8; ++j) v8[j] = (bf16)s[(cb + j) * 65 + px];
        *(bf16x8*)(dstp + cb) = v8;
    }
}

// ---- convert+transpose weights to bf16 + init pool atomics ----
__global__ void wconv_kernel(const float* __restrict__ w_qkv,
                             const float* __restrict__ w_proj,
                             bf16* __restrict__ wqkvT,
                             bf16* __restrict__ wprojT,
                             float* __restrict__ pool_sum,
                             unsigned* __restrict__ pool_maxkey)
{
    int id = blockIdx.x * 256 + threadIdx.x;
    if (blockIdx.x == 0 && threadIdx.x < 256) {
        pool_sum[threadIdx.x] = 0.f;        pool_maxkey[threadIdx.x] = 0u;
        pool_sum[256 + threadIdx.x] = 0.f;  pool_maxkey[256 + threadIdx.x] = 0u;
    }
    if (id < 49152) {                       // 384*128
        int co = id >> 7, c = id & 127;
        wqkvT[id] = (bf16)w_qkv[c * 384 + co];
    } else {
        int id2 = id - 49152;               // 128*128
        int co = id2 >> 7, c = id2 & 127;
        wprojT[id2] = (bf16)w_proj[c * 128 + co];
    }
}

// ---- fused window/grid relative attention, one 8x8 window per block ----
// STAGE 0: pixel = (wr*8+i, wc*8+j), in=xT, out=x1T (NHWC bf16)
// STAGE 1: pixel = (i*32+wr, j*32+wc), in=x1T, out=x2 (NHWC fp32) + pooling
template<int STAGE>
__global__ __launch_bounds__(256, 2)
void attn_kernel(const bf16* __restrict__ xT, bf16* __restrict__ x1T,
                 float* __restrict__ x2,
                 const bf16* __restrict__ wqkvT, const bf16* __restrict__ wprojT,
                 const float* __restrict__ b_qkv, const float* __restrict__ b_proj,
                 const float* __restrict__ rpb,
                 float* __restrict__ pool_sum, unsigned* __restrict__ pool_maxkey)
{
    __shared__ bf16 s_a[64 * 128];     // input window [n][c] (swz) — lives to epilogue (residual)
    __shared__ bf16 s_b[4 * 2 * QKR];  // per-head q,k (stride-40 rows); P aliases per head
    __shared__ bf16 s_v[4 * 32 * 64];  // per-head V^T [d][m] -> later attn output [n][c]
    __shared__ float s_rpb[225 * 4];

    const int tid = threadIdx.x;
    const int lane = tid & 63;
    const int wv = tid >> 6;     // wave = head = GEMM column chunk
    const int lr = lane & 15;
    const int lg = lane >> 4;

    const int blk = (blockIdx.x & 7) * 512 + (blockIdx.x >> 3);  // XCD-bijective
    const int b  = blk >> 10;
    const int wr = (blk >> 5) & 31;
    const int wc = blk & 31;

    // ---- stage input window (NHWC bf16) into LDS: 64B dense segments ----
    {
        int n = tid >> 2, piece = tid & 3;
        int ii = n >> 3, jj = n & 7;
        int ph = (STAGE == 0) ? (wr * 8 + ii) : (ii * 32 + wr);
        int pw = (STAGE == 0) ? (wc * 8 + jj) : (jj * 32 + wc);
        const bf16* src = xT + ((size_t)b * 65536 + (size_t)ph * 256 + pw) * 128;
#pragma unroll
        for (int k = 0; k < 4; ++k) {
            int c = k * 64 + piece * 16;   // wait: 4 pieces * 16B? (see note below)
            // 128 c-elems = 256B = 16 chunks of 16B: chunk id = k*4+piece
            int cc = (k * 4 + piece) * 8;
            bf16x8 v = *(const bf16x8*)(src + cc);
            *(bf16x8*)&s_a[(n * 128 + cc) ^ ((n & 15) << 3)] = v;
            (void)c;
        }
    }
    for (int i = tid; i < 900; i += 256) s_rpb[i] = rpb[i];

    // preload qkv weight B-fragments (this wave's 96 output cols)
    bf16x8 wB[6][4];
#pragma unroll
    for (int nt = 0; nt < 6; ++nt) {
        int co = wv * 96 + nt * 16 + lr;
        const bf16* rp = wqkvT + co * 128 + lg * 8;
#pragma unroll
        for (int ks = 0; ks < 4; ++ks)
            wB[nt][ks] = *(const bf16x8*)(rp + ks * 32);
    }

    __syncthreads();

    // ---- QKV GEMM: qkv[n][co] = sum_c xw[n][c] * wqkv[c][co] ----
    f32x4 qacc[4][6];
#pragma unroll
    for (int mt = 0; mt < 4; ++mt)
#pragma unroll
        for (int nt = 0; nt < 6; ++nt)
            qacc[mt][nt] = (f32x4){0.f, 0.f, 0.f, 0.f};

#pragma unroll
    for (int ks = 0; ks < 4; ++ks) {
        bf16x8 a[4];
#pragma unroll
        for (int mt = 0; mt < 4; ++mt) {
            int n = mt * 16 + lr;
            a[mt] = *(const bf16x8*)&s_a[(n * 128 + ks * 32 + lg * 8) ^ ((n & 15) << 3)];
        }
#pragma unroll
        for (int mt = 0; mt < 4; ++mt)
#pragma unroll
            for (int nt = 0; nt < 6; ++nt)
                qacc[mt][nt] = MFMA16(a[mt], wB[nt][ks], qacc[mt][nt]);
    }

    // scatter q,k into s_b (stride-40 swizzled rows) and v^T into s_v, + bias
#pragma unroll
    for (int nt = 0; nt < 6; ++nt) {
        int co = wv * 96 + nt * 16 + lr;
        float bias = b_qkv[co];
        int qsel = co >> 7;          // 0=q 1=k 2=v (uniform per nt)
        int hh = (co >> 5) & 3;
        int d = co & 31;
#pragma unroll
        for (int mt = 0; mt < 4; ++mt) {
            int n0 = mt * 16 + lg * 4;
            if (qsel < 2) {
#pragma unroll
                for (int r = 0; r < 4; ++r) {
                    int n = n0 + r;
                    s_b[(hh * 2 + qsel) * QKR + n * QKS + (d ^ QKSWZ(n))] =
                        (bf16)(qacc[mt][nt][r] + bias);
                }
            } else {
                bf16x4 v4;
#pragma unroll
                for (int r = 0; r < 4; ++r) v4[r] = (bf16)(qacc[mt][nt][r] + bias);
                int idx = ((hh * 32 + d) * 64 + n0) ^ ((d & 7) << 3);
                *(bf16x4*)&s_v[idx] = v4;
            }
        }
    }

    __syncthreads();

    // ---- attention, head h = wv.  S^T = K*Q^T so softmax rows are mostly lane-local
    const int h = wv;
    f32x4 sacc[4][4];   // [mt][nt]: S^T[m][n], m=mt*16+lg*4+r, n=nt*16+lr
#pragma unroll
    for (int mt = 0; mt < 4; ++mt)
#pragma unroll
        for (int nt = 0; nt < 4; ++nt)
            sacc[mt][nt] = (f32x4){0.f, 0.f, 0.f, 0.f};
    {
        bf16x8 ka[4], qb[4];
#pragma unroll
        for (int t = 0; t < 4; ++t) {
            int m = t * 16 + lr;
            ka[t] = *(const bf16x8*)&s_b[(h * 2 + 1) * QKR + m * QKS + ((lg * 8) ^ QKSWZ(m))];
            qb[t] = *(const bf16x8*)&s_b[(h * 2 + 0) * QKR + m * QKS + ((lg * 8) ^ QKSWZ(m))];
        }
#pragma unroll
        for (int mt = 0; mt < 4; ++mt)
#pragma unroll
            for (int nt = 0; nt < 4; ++nt)
                sacc[mt][nt] = MFMA16(ka[mt], qb[nt], sacc[mt][nt]);
    }

    // scale 0.5 (= HEADS^-0.5), + Swin relative bias, softmax over m
    float inv[4];
#pragma unroll
    for (int nt = 0; nt < 4; ++nt) {
        int n = nt * 16 + lr;
        float mx = -1e30f;
#pragma unroll
        for (int mt = 0; mt < 4; ++mt)
#pragma unroll
            for (int r = 0; r < 4; ++r) {
                int m = mt * 16 + lg * 4 + r;
                int rel = ((n >> 3) - (m >> 3) + 7) * 15 + ((n & 7) - (m & 7) + 7);
                float lgt = sacc[mt][nt][r] * 0.5f + s_rpb[rel * 4 + h];
                sacc[mt][nt][r] = lgt;
                mx = fmaxf(mx, lgt);
            }
        mx = fmaxf(mx, __shfl_xor(mx, 16));
        mx = fmaxf(mx, __shfl_xor(mx, 32));
        float sum = 0.f;
#pragma unroll
        for (int mt = 0; mt < 4; ++mt)
#pragma unroll
            for (int r = 0; r < 4; ++r) {
                float p = __expf(sacc[mt][nt][r] - mx);
                sacc[mt][nt][r] = p;
                sum += p;
            }
        sum += __shfl_xor(sum, 16);
        sum += __shfl_xor(sum, 32);
        inv[nt] = 1.f / sum;
    }

    // write P as [n][m] bf16 into this head's (dead) q/k region
    bf16* s_p = s_b + h * 2 * QKR;
#pragma unroll
    for (int nt = 0; nt < 4; ++nt) {
        int n = nt * 16 + lr;
#pragma unroll
        for (int mt = 0; mt < 4; ++mt) {
            bf16x4 v4;
#pragma unroll
            for (int r = 0; r < 4; ++r) v4[r] = (bf16)(sacc[mt][nt][r] * inv[nt]);
            int idx = (n * 64 + mt * 16 + lg * 4) ^ ((n & 7) << 3);
            *(bf16x4*)&s_p[idx] = v4;
        }
    }
    asm volatile("s_waitcnt lgkmcnt(0)" ::: "memory"); // wave-local P visible to all lanes
    __builtin_amdgcn_sched_barrier(0);

    // PV: out^T[d][n] = sum_m V^T[d][m] * P^T[m][n]
    f32x4 oacc[2][4];
#pragma unroll
    for (int dt = 0; dt < 2; ++dt)
#pragma unroll
        for (int nt = 0; nt < 4; ++nt)
            oacc[dt][nt] = (f32x4){0.f, 0.f, 0.f, 0.f};
#pragma unroll
    for (int ks = 0; ks < 2; ++ks) {
        bf16x8 va[2], pb[4];
#pragma unroll
        for (int dt = 0; dt < 2; ++dt) {
            int d = dt * 16 + lr;
            va[dt] = *(const bf16x8*)&s_v[((h * 32 + d) * 64 + ks * 32 + lg * 8) ^ ((d & 7) << 3)];
        }
#pragma unroll
        for (int nt = 0; nt < 4; ++nt) {
            int n = nt * 16 + lr;
            pb[nt] = *(const bf16x8*)&s_p[(n * 64 + ks * 32 + lg * 8) ^ ((n & 7) << 3)];
        }
#pragma unroll
        for (int dt = 0; dt < 2; ++dt)
#pragma unroll
            for (int nt = 0; nt < 4; ++nt)
                oacc[dt][nt] = MFMA16(va[dt], pb[nt], oacc[dt][nt]);
    }

    __syncthreads();   // all PV reads of s_v/s_p done before attnout overwrites s_v

    // attn output -> s_v as [n][c], c = h*32 + d
#pragma unroll
    for (int dt = 0; dt < 2; ++dt)
#pragma unroll
        for (int nt = 0; nt < 4; ++nt) {
            int n = nt * 16 + lr;
            int c0 = h * 32 + dt * 16 + lg * 4;
            bf16x4 v4;
#pragma unroll
            for (int r = 0; r < 4; ++r) v4[r] = (bf16)oacc[dt][nt][r];
            int idx = (n * 128 + c0) ^ ((n & 15) << 3);
            *(bf16x4*)&s_v[idx] = v4;
        }

    __syncthreads();

    // ---- proj: x1^T[co][n] = sum_c wproj[c][co] * attn[n][c] ----
    f32x4 pacc[2][4];
#pragma unroll
    for (int ct = 0; ct < 2; ++ct)
#pragma unroll
        for (int nt = 0; nt < 4; ++nt)
            pacc[ct][nt] = (f32x4){0.f, 0.f, 0.f, 0.f};
#pragma unroll
    for (int ks = 0; ks < 4; ++ks) {
        bf16x8 wa[2], ab[4];
#pragma unroll
        for (int ct = 0; ct < 2; ++ct) {
            int co = wv * 32 + ct * 16 + lr;
            wa[ct] = *(const bf16x8*)(wprojT + co * 128 + ks * 32 + lg * 8);
        }
#pragma unroll
        for (int nt = 0; nt < 4; ++nt) {
            int n = nt * 16 + lr;
            ab[nt] = *(const bf16x8*)&s_v[(n * 128 + ks * 32 + lg * 8) ^ ((n & 15) << 3)];
        }
#pragma unroll
        for (int ct = 0; ct < 2; ++ct)
#pragma unroll
            for (int nt = 0; nt < 4; ++nt)
                pacc[ct][nt] = MFMA16(wa[ct], ab[nt], pacc[ct][nt]);
    }

    // ---- epilogue: residual from LDS (s_a), coalesced NHWC writes ----
    float bp[2][4];
#pragma unroll
    for (int ct = 0; ct < 2; ++ct)
#pragma unroll
        for (int r = 0; r < 4; ++r) bp[ct][r] = b_proj[wv * 32 + ct * 16 + lg * 4 + r];

    float ps[2][4], pm[2][4];
    if constexpr (STAGE == 1) {
#pragma unroll
        for (int ct = 0; ct < 2; ++ct)
#pragma unroll
            for (int r = 0; r < 4; ++r) { ps[ct][r] = 0.f; pm[ct][r] = -1e30f; }
    }

#pragma unroll
    for (int ct = 0; ct < 2; ++ct)
#pragma unroll
        for (int nt = 0; nt < 4; ++nt) {
            int n = nt * 16 + lr;
            int ii = n >> 3, jj = n & 7;
            int ph = (STAGE == 0) ? (wr * 8 + ii) : (ii * 32 + wr);
            int pw = (STAGE == 0) ? (wc * 8 + jj) : (jj * 32 + wc);
            size_t px = (size_t)b * 65536 + (size_t)ph * 256 + pw;
            int c0 = wv * 32 + ct * 16 + lg * 4;
            bf16x4 res = *(const bf16x4*)&s_a[(n * 128 + c0) ^ ((n & 15) << 3)];
            if constexpr (STAGE == 0) {
                bf16x4 o;
#pragma unroll
                for (int r = 0; r < 4; ++r)
                    o[r] = (bf16)((float)res[r] + bp[ct][r] + pacc[ct][nt][r]);
                *(bf16x4*)&x1T[px * 128 + c0] = o;
            } else {
                f32x4 o;
#pragma unroll
                for (int r = 0; r < 4; ++r) {
                    float v = (float)res[r] + bp[ct][r] + pacc[ct][nt][r];
                    o[r] = v;
                    ps[ct][r] += v;
                    pm[ct][r] = fmaxf(pm[ct][r], v);
                }
                *(f32x4*)&x2[px * 128 + c0] = o;
            }
        }

    if constexpr (STAGE == 1) {
#pragma unroll
        for (int ct = 0; ct < 2; ++ct)
#pragma unroll
            for (int r = 0; r < 4; ++r) {
                float s = ps[ct][r], m = pm[ct][r];
#pragma unroll
                for (int o = 1; o < 16; o <<= 1) {
                    s += __shfl_xor(s, o);
                    m = fmaxf(m, __shfl_xor(m, o));
                }
                if (lr == 0) {
                    int cout = wv * 32 + ct * 16 + lg * 4 + r;
                    atomicAdd(&pool_sum[b * 128 + cout], s);
                    unsigned u = __float_as_uint(m);
                    unsigned kk = (u & 0x80000000u) ? ~u : (u | 0x80000000u);
                    atomicMax(&pool_maxkey[b * 128 + cout], kk);
                }
            }
    }
}

// ---- gate = sigmoid( (relu(avg@W1)+relu(mx@W1)) @ W2 ) ----
__global__ void gate_kernel(const float* __restrict__ pool_sum,
                            const unsigned* __restrict__ pool_maxkey,
                            const float* __restrict__ w1, const float* __restrict__ w2,
                            float* __restrict__ gate)
{
    __shared__ float la[512], lm[512], s1[512];
    int t = threadIdx.x;
    la[t] = pool_sum[t] * (1.f / 65536.f);
    unsigned k = pool_maxkey[t];
    lm[t] = __uint_as_float((k & 0x80000000u) ? (k ^ 0x80000000u) : ~k);
    __syncthreads();
    int b = t >> 7, co = t & 127;
    float a1 = 0.f, m1 = 0.f;
    for (int c = 0; c < 128; ++c) {
        float w = w1[c * 128 + co];
        a1 += la[b * 128 + c] * w;
        m1 += lm[b * 128 + c] * w;
    }
    s1[t] = fmaxf(a1, 0.f) + fmaxf(m1, 0.f);
    __syncthreads();
    float g = 0.f;
    for (int c = 0; c < 128; ++c) g += s1[b * 128 + c] * w2[c * 128 + co];
    gate[t] = 1.f / (1.f + __expf(-g));
}

// ---- k4: x2 NHWC fp32 * gate -> out NCHW fp32 (tiled LDS transpose) ----
__global__ __launch_bounds__(256) void tout_kernel(const float* __restrict__ x2,
                                                   const float* __restrict__ gate,
                                                   float* __restrict__ out)
{
    __shared__ float s[128 * 68];
    __shared__ __align__(16) float sg[128];
    const int blk = blockIdx.x;
    const int b = blk >> 10;
    const int px0 = (blk & 1023) * 64;
    const int t = threadIdx.x;
    if (t < 128) sg[t] = gate[b * 128 + t];
    __syncthreads();
    const f32x4* src = (const f32x4*)(x2 + ((size_t)b * 65536 + px0) * 128);
#pragma unroll
    for (int i = 0; i < 8; ++i) {
        int idx4 = t + i * 256;
        int px = idx4 >> 5, c4 = idx4 & 31;
        f32x4 v = src[idx4];
        f32x4 g = *(const f32x4*)&sg[c4 * 4];
        v *= g;
        int pxs = px ^ ((c4 & 7) << 3);
#pragma unroll
        for (int j = 0; j < 4; ++j) s[(c4 * 4 + j) * 68 + pxs] = v[j];
    }
    __syncthreads();
    int cg = t >> 4, pl = (t & 15) * 4;
#pragma unroll
    for (int i = 0; i < 8; ++i) {
        int c = cg + i * 16;
        int pp = pl ^ (((c >> 2) & 7) << 3);
        f32x4 w = *(const f32x4*)&s[c * 68 + pp];
        *(f32x4*)&out[((size_t)(b * 128 + c)) * 65536 + px0 + pl] = w;
    }
}

extern "C" void kernel_launch(void* const* d_in, const int* in_sizes, int n_in,
                              void* d_out, int out_size, void* d_ws, size_t ws_size,
                              hipStream_t stream)
{
    const float* x      = (const float*)d_in[0];
    const float* w_qkv  = (const float*)d_in[1];
    const float* b_qkv  = (const float*)d_in[2];
    const float* w_proj = (const float*)d_in[3];
    const float* b_proj = (const float*)d_in[4];
    const float* rpb    = (const float*)d_in[5];
    const float* cf_w1  = (const float*)d_in[6];
    const float* cf_w2  = (const float*)d_in[7];
    float* out = (float*)d_out;

    char* ws = (char*)d_ws;
    // ws[0:64MB] = xT (bf16 NHWC, dead after attn<0>)
    // ws[0:128MB] = x2 (fp32 NHWC, written by attn<1>, read by tout)
    bf16*  xT = (bf16*)ws;
    float* x2 = (float*)ws;
    char* tail = ws + 134217728;
    bf16*     wqkvT   = (bf16*)tail;                 // 98304 B
    bf16*     wprojT  = (bf16*)(tail + 98304);       // 32768 B
    float*    poolsum = (float*)(tail + 131072);     // 2048 B
    unsigned* poolmax = (unsigned*)(tail + 133120);  // 2048 B
    float*    gate    = (float*)(tail + 135168);     // 2048 B
    bf16*     x1T     = (bf16*)d_out;                // 64 MB region, dead after attn<1>

    tin_kernel<<<4096, 256, 0, stream>>>(x, xT);
    wconv_kernel<<<256, 256, 0, stream>>>(w_qkv, w_proj, wqkvT, wprojT, poolsum, poolmax);
    attn_kernel<0><<<4096, 256, 0, stream>>>(xT, x1T, nullptr, wqkvT, wprojT,
                                             b_qkv, b_proj, rpb, poolsum, poolmax);
    attn_kernel<1><<<4096, 256, 0, stream>>>(x1T, nullptr, x2, wqkvT, wprojT,
                                             b_qkv, b_proj, rpb, poolsum, poolmax);
    gate_kernel<<<1, 512, 0, stream>>>(poolsum, poolmax, cf_w1, cf_w2, gate);
    tout_kernel<<<4096, 256, 0, stream>>>(x2, gate, out);
}